// Round 10
// baseline (56.740 us; speedup 1.0000x reference)
//
#include <hip/hip_runtime.h>
#include <hip/hip_fp16.h>

// Damped electrostatics with shifted-force cutoff.
// Packed atom table in d_ws, 32 B/atom (3.2 MB, L2-resident per XCD):
//   word0 (f32x4): q, dip.x, dip.y, dip.z
//   word1 (u32x4): fp16x2{t00,t11}, fp16x2{t22,s01}, fp16x2{s02,s12}, pad
// Edge kernel: grid-stride, 2-deep software pipeline —
//   iter k: issue gathers[k+1] (idx[k+1] arrived, issued at k-1),
//           issue streams[k+2], compute edge k from gathers[k] (already
//           retired by the vmcnt wait on the younger idx[k+1]).
// Gather latency is hidden behind one full iteration. Fast rsq intrinsics
// replace IEEE div/sqrt chains. d recomputed from vec (d == |v|).

#define KEHALF      7.199822675975274f

typedef float    f32x4 __attribute__((ext_vector_type(4)));
typedef unsigned u32x4 __attribute__((ext_vector_type(4)));

__device__ __forceinline__ unsigned pack_h2(float a, float b) {
    return __builtin_bit_cast(unsigned, __floats2half2_rn(a, b));
}
__device__ __forceinline__ float2 unpack_h2(unsigned u) {
    return __half22float2(__builtin_bit_cast(__half2, u));
}

__global__ __launch_bounds__(256) void pack_atoms_kernel(
    const float* __restrict__ q,
    const float* __restrict__ dip,
    const float* __restrict__ quad,
    f32x4* __restrict__ table,        // [N,2] 16B words
    int N)
{
    int i = blockIdx.x * blockDim.x + threadIdx.x;
    if (i >= N) return;
    const float* dp = dip + 3 * (size_t)i;
    const float* qp = quad + 9 * (size_t)i;

    f32x4 w0 = {q[i], dp[0], dp[1], dp[2]};

    float q00 = qp[0], q01 = qp[1], q02 = qp[2];
    float q10 = qp[3], q11 = qp[4], q12 = qp[5];
    float q20 = qp[6], q21 = qp[7], q22 = qp[8];
    float trQ3 = (q00 + q11 + q22) * (1.0f / 3.0f);

    u32x4 w1 = {pack_h2(q00 - trQ3, q11 - trQ3),
                pack_h2(q22 - trQ3, q01 + q10),
                pack_h2(q02 + q20, q12 + q21),
                0u};

    table[2 * (size_t)i + 0] = w0;
    table[2 * (size_t)i + 1] = __builtin_bit_cast(f32x4, w1);
}

__device__ __forceinline__ float edge_energy(
    float vx, float vy, float vz,
    f32x4 au, f32x4 av, f32x4 bqf)
{
    u32x4 bv = __builtin_bit_cast(u32x4, bqf);

    float d2 = vx * vx + vy * vy + vz * vz;
    float inv_d = __builtin_amdgcn_rsqf(d2);     // 1/|v|, ~1ulp
    float d = d2 * inv_d;
    float inv_d2 = inv_d * inv_d;

    // poly5 switch, cutoff_sr = 4
    float x = d * 0.25f;
    float x2 = x * x;
    float x3 = x2 * x;
    float sw = 1.0f - x3 * (10.0f - 15.0f * x + 6.0f * x2);
    sw = (x < 1.0f) ? sw : 0.0f;
    float chi = sw * __builtin_amdgcn_rsqf(d2 + 1.0f) + (1.0f - sw) * inv_d;

    // shifted-force corrections (cutoff = 10)
    float c1 = chi - (0.2f   - 0.01f   * d);
    float chi2 = chi * chi;
    float chi3 = chi2 * chi;
    float c2 = chi2 - (0.03f  - 0.002f  * d);
    float c3 = chi3 - (0.004f - 0.0003f * d);

    float qu = au.x, qv = av.x;
    float Ee = qu * qv * c1;

    float dot_uv = (vx * av.y + vy * av.z + vz * av.w) * inv_d;
    float dot_vu = (vx * au.y + vy * au.z + vz * au.w) * inv_d;
    float dd     = au.y * av.y + au.z * av.z + au.w * av.w;

    Ee += 2.0f * qu * dot_uv * c2;
    Ee += (dd - 3.0f * dot_uv * dot_vu) * c3;

    // traceless quadrupole contraction (uses sum(v_i^2) == d^2)
    float2 h0 = unpack_h2(bv.x);   // t00, t11
    float2 h1 = unpack_h2(bv.y);   // t22, s01
    float2 h2 = unpack_h2(bv.z);   // s02, s12
    float num = h0.x * vx * vx + h0.y * vy * vy + h1.x * vz * vz
              + h1.y * vx * vy + h2.x * vx * vz + h2.y * vy * vz;
    Ee += qu * (num * inv_d2) * c3;

    Ee *= KEHALF;
    return (d <= 10.0f) ? Ee : 0.0f;
}

__global__ __launch_bounds__(256) void damped_elec_pipe2(
    const f32x4* __restrict__ table,  // [N,2]
    const float* __restrict__ vec,    // [E,3]
    const int*   __restrict__ idx_u,  // [E]
    const int*   __restrict__ idx_v,  // [E]
    float*       __restrict__ out,    // [E]
    int E)
{
    const int tid = blockIdx.x * blockDim.x + threadIdx.x;
    const int stride = gridDim.x * blockDim.x;

    int i0 = tid;
    if (i0 >= E) return;

    // ---- prologue ----
    // streams for edge i0
    int u0 = __builtin_nontemporal_load(idx_u + i0);
    int v0 = __builtin_nontemporal_load(idx_v + i0);
    float ax = __builtin_nontemporal_load(vec + 3 * (size_t)i0 + 0);
    float ay = __builtin_nontemporal_load(vec + 3 * (size_t)i0 + 1);
    float az = __builtin_nontemporal_load(vec + 3 * (size_t)i0 + 2);
    // gathers for edge i0 (in flight entering the loop)
    f32x4 au0 = table[2 * (size_t)u0];
    f32x4 av0 = table[2 * (size_t)v0 + 0];
    f32x4 bq0 = table[2 * (size_t)v0 + 1];

    // streams for edge i1
    int i1 = i0 + stride;
    bool has1 = i1 < E;
    int u1 = 0, v1 = 0;
    float bx = 0.f, by = 0.f, bz = 0.f;
    if (has1) {
        u1 = __builtin_nontemporal_load(idx_u + i1);
        v1 = __builtin_nontemporal_load(idx_v + i1);
        bx = __builtin_nontemporal_load(vec + 3 * (size_t)i1 + 0);
        by = __builtin_nontemporal_load(vec + 3 * (size_t)i1 + 1);
        bz = __builtin_nontemporal_load(vec + 3 * (size_t)i1 + 2);
    }

    for (;;) {
        // 1) issue gathers for the NEXT edge (waits on idx[i1] stream;
        //    by in-order vmcnt retirement this also retires gathers[i0])
        f32x4 au1 = {}, av1 = {}, bq1 = {};
        if (has1) {
            au1 = table[2 * (size_t)u1];
            av1 = table[2 * (size_t)v1 + 0];
            bq1 = table[2 * (size_t)v1 + 1];
        }

        // 2) issue streams for edge i+2
        int i2 = i1 + stride;
        bool has2 = has1 && (i2 < E);
        int u2 = 0, v2 = 0;
        float cx = 0.f, cy = 0.f, cz = 0.f;
        if (has2) {
            u2 = __builtin_nontemporal_load(idx_u + i2);
            v2 = __builtin_nontemporal_load(idx_v + i2);
            cx = __builtin_nontemporal_load(vec + 3 * (size_t)i2 + 0);
            cy = __builtin_nontemporal_load(vec + 3 * (size_t)i2 + 1);
            cz = __builtin_nontemporal_load(vec + 3 * (size_t)i2 + 2);
        }

        // 3) compute current edge (gathers already resident)
        float r = edge_energy(ax, ay, az, au0, av0, bq0);
        __builtin_nontemporal_store(r, out + i0);

        if (!has1) break;

        // rotate pipeline state
        i0 = i1; ax = bx; ay = by; az = bz;
        au0 = au1; av0 = av1; bq0 = bq1;
        i1 = i2; u1 = u2; v1 = v2; bx = cx; by = cy; bz = cz;
        has1 = has2;
    }
}

// Fallback if ws_size is too small for the packed table.
__global__ __launch_bounds__(256) void damped_elec_unpacked(
    const float* __restrict__ q,
    const float* __restrict__ dip,
    const float* __restrict__ quad,
    const float* __restrict__ vec,
    const int*   __restrict__ idx_u,
    const int*   __restrict__ idx_v,
    float*       __restrict__ out,
    int E)
{
    int i = blockIdx.x * blockDim.x + threadIdx.x;
    if (i >= E) return;
    float vx = vec[3 * (size_t)i + 0];
    float vy = vec[3 * (size_t)i + 1];
    float vz = vec[3 * (size_t)i + 2];
    int u = idx_u[i];
    int v = idx_v[i];
    const float* pu = dip + 3 * (size_t)u;
    const float* pv = dip + 3 * (size_t)v;
    const float* pq = quad + 9 * (size_t)v;

    f32x4 au = {q[u], pu[0], pu[1], pu[2]};
    f32x4 av = {q[v], pv[0], pv[1], pv[2]};
    float trQ3 = (pq[0] + pq[4] + pq[8]) * (1.0f / 3.0f);
    u32x4 bv = {pack_h2(pq[0] - trQ3, pq[4] - trQ3),
                pack_h2(pq[8] - trQ3, pq[1] + pq[3]),
                pack_h2(pq[2] + pq[6], pq[5] + pq[7]),
                0u};
    out[i] = edge_energy(vx, vy, vz, au, av, __builtin_bit_cast(f32x4, bv));
}

extern "C" void kernel_launch(void* const* d_in, const int* in_sizes, int n_in,
                              void* d_out, int out_size, void* d_ws, size_t ws_size,
                              hipStream_t stream) {
    const float* q    = (const float*)d_in[0];  // atomic_charges      [N]
    const float* dip  = (const float*)d_in[1];  // atomic_dipoles      [N,3]
    const float* quad = (const float*)d_in[2];  // atomic_quadrupoles  [N,3,3]
    const float* vec  = (const float*)d_in[3];  // vectors_uv          [E,3]
    const int*   iu   = (const int*)d_in[5];    // idx_u               [E]
    const int*   iv   = (const int*)d_in[6];    // idx_v               [E]
    float* out = (float*)d_out;

    int N = in_sizes[0];
    int E = in_sizes[4];
    int block = 256;

    size_t need = (size_t)N * 32;
    if (ws_size >= need) {
        f32x4* table = (f32x4*)d_ws;
        int pgrid = (N + block - 1) / block;
        pack_atoms_kernel<<<pgrid, block, 0, stream>>>(q, dip, quad, table, N);
        // 2048 blocks x 256 = 8 blocks/CU (full wave residency at low VGPR);
        // each thread pipelines ~6 edges.
        damped_elec_pipe2<<<2048, block, 0, stream>>>(table, vec, iu, iv, out, E);
    } else {
        int egrid = (E + block - 1) / block;
        damped_elec_unpacked<<<egrid, block, 0, stream>>>(q, dip, quad, vec, iu, iv, out, E);
    }
}